// Round 3
// baseline (724.114 us; speedup 1.0000x reference)
//
#include <hip/hip_runtime.h>
#include <hip/hip_bf16.h>

// ---------------------------------------------------------------------------
// Problem constants
// ---------------------------------------------------------------------------
#define NUM_B     32
#define A_TOTAL   6300
#define SEG_TOTAL 201600
#define TPS       256          // segments per tile (all scales)
#define TPS_SHIFT 8
#define NT0       600          // 153600/256
#define NT1       150          // 38400/256
#define NT2       38           // ceil(9600/256), last tile has 128 segs
#define NT_TOT    788
#define NBLK0     512
#define NBLK1     256
#define NBLK2     128
#define NBLK_TOT  896
// counts/rel matrix row bases (entries = tile-row * nblk)
#define SRB0      0
#define SRB1      307200       // NT0*NBLK0
#define SRB2      345600       // SRB1 + NT1*NBLK1
#define MAT_TOT   350464       // SRB2 + NT2*NBLK2

struct Ptrs {
    const float* cls; const float* reg; const float* obj;
    const float* pos; const int* batch;
    int n, chunk;
};
struct Args { Ptrs s[3]; };

__device__ __forceinline__ void scale_consts(int s, int& HW, int& W, int& H,
                                             float& st, int& nt, int& toff,
                                             int& aoff, int& nblk, int& srb,
                                             int& nseg)
{
    if (s == 0)      { HW=4800; W=80; H=60; st=3.f;  nt=NT0; toff=0;       aoff=0;    nblk=NBLK0; srb=SRB0; nseg=153600; }
    else if (s == 1) { HW=1200; W=40; H=30; st=6.f;  nt=NT1; toff=NT0;     aoff=4800; nblk=NBLK1; srb=SRB1; nseg=38400;  }
    else             { HW=300;  W=20; H=15; st=12.f; nt=NT2; toff=NT0+NT1; aoff=6000; nblk=NBLK2; srb=SRB2; nseg=9600;   }
}

__device__ __forceinline__ int block_scale(int bid, int& lb)
{
    if (bid < NBLK0)         { lb = bid;                   return 0; }
    if (bid < NBLK0 + NBLK1) { lb = bid - NBLK0;           return 1; }
    lb = bid - (NBLK0 + NBLK1);                            return 2;
}

__device__ __forceinline__ int tile_scale(int gt, int& lt)
{
    if (gt < NT0)       { lt = gt;             return 0; }
    if (gt < NT0 + NT1) { lt = gt - NT0;       return 1; }
    lt = gt - (NT0 + NT1);                     return 2;
}

// ---------------------------------------------------------------------------
// Pass 1: per-(block,tile) histogram -> counts_mat (fully written every call)
// ---------------------------------------------------------------------------
__global__ __launch_bounds__(256) void p1_count(Args a, int* __restrict__ counts_mat)
{
    __shared__ int hist[NT0];
    int lb; int s = block_scale(blockIdx.x, lb);
    int HW,W,H,nt,toff,aoff,nblk,srb,nseg; float st;
    scale_consts(s,HW,W,H,st,nt,toff,aoff,nblk,srb,nseg);
    const Ptrs& P = a.s[s];

    for (int t = threadIdx.x; t < nt; t += 256) hist[t] = 0;
    __syncthreads();

    int start = lb * P.chunk;
    int end   = min(start + P.chunk, P.n);
    const float2* pos = reinterpret_cast<const float2*>(P.pos);
    for (int i = start + (int)threadIdx.x; i < end; i += 256) {
        float2 p = pos[i];
        int b = P.batch[i];
        int col = min(max((int)(p.x / st), 0), W - 1);
        int row = min(max((int)(p.y / st), 0), H - 1);
        int lseg = b * HW + row * W + col;
        atomicAdd(&hist[lseg >> TPS_SHIFT], 1);
    }
    __syncthreads();
    for (int t = threadIdx.x; t < nt; t += 256)
        counts_mat[srb + t * nblk + lb] = hist[t];
}

// ---------------------------------------------------------------------------
// Scan A: one block per tile — exclusive scan over that tile's per-block
// counts -> rel_base; tile total -> tile_tot.
// ---------------------------------------------------------------------------
__global__ __launch_bounds__(512) void p_scanA(const int* __restrict__ counts_mat,
                                               int* __restrict__ rel_base,
                                               int* __restrict__ tile_tot)
{
    __shared__ int buf[512];
    int gt = blockIdx.x, lt;
    int s = tile_scale(gt, lt);
    int HW,W,H,nt,toff,aoff,nblk,srb,nseg; float st;
    scale_consts(s,HW,W,H,st,nt,toff,aoff,nblk,srb,nseg);
    int row = srb + lt * nblk;
    int t = threadIdx.x;
    int v = (t < nblk) ? counts_mat[row + t] : 0;
    buf[t] = v;
    __syncthreads();
    int x = v;
    for (int off = 1; off < 512; off <<= 1) {
        int y = (t >= off) ? buf[t - off] : 0;
        __syncthreads();
        x += y;
        buf[t] = x;
        __syncthreads();
    }
    if (t < nblk) rel_base[row + t] = x - v;
    if (t == nblk - 1) tile_tot[gt] = x;
}

// ---------------------------------------------------------------------------
// Scan B: exclusive scan over 788 tile totals -> tile_base (one block)
// ---------------------------------------------------------------------------
__global__ __launch_bounds__(1024) void p_scanB(const int* __restrict__ tile_tot,
                                                int* __restrict__ tile_base)
{
    __shared__ int buf[1024];
    int t = threadIdx.x;
    int v = (t < NT_TOT) ? tile_tot[t] : 0;
    buf[t] = v;
    __syncthreads();
    int x = v;
    for (int off = 1; off < 1024; off <<= 1) {
        int y = (t >= off) ? buf[t - off] : 0;
        __syncthreads();
        x += y;
        buf[t] = x;
        __syncthreads();
    }
    if (t < NT_TOT) tile_base[t] = x - v;
}

// ---------------------------------------------------------------------------
// Pass 2: single sweep — LDS cursors pre-seeded from rel_base+tile_base,
// write 32 B payload per point into tile-sorted order. No global atomics.
// payload: {reg.xyzw} {obj, cls.x, cls.y, scale-local seg}
// ---------------------------------------------------------------------------
__global__ __launch_bounds__(256) void p2_scatter(Args a,
                                                  const int* __restrict__ rel_base,
                                                  const int* __restrict__ tile_base,
                                                  float4* __restrict__ pay)
{
    __shared__ int cur[NT0];
    int lb; int s = block_scale(blockIdx.x, lb);
    int HW,W,H,nt,toff,aoff,nblk,srb,nseg; float st;
    scale_consts(s,HW,W,H,st,nt,toff,aoff,nblk,srb,nseg);
    const Ptrs& P = a.s[s];

    for (int t = threadIdx.x; t < nt; t += 256)
        cur[t] = tile_base[toff + t] + rel_base[srb + t * nblk + lb];
    __syncthreads();

    int start = lb * P.chunk;
    int end   = min(start + P.chunk, P.n);
    const float2* pos  = reinterpret_cast<const float2*>(P.pos);
    const float4* reg4 = reinterpret_cast<const float4*>(P.reg);
    const float2* cls2 = reinterpret_cast<const float2*>(P.cls);

    for (int i = start + (int)threadIdx.x; i < end; i += 256) {
        float2 p = pos[i];
        int b = P.batch[i];
        int col = min(max((int)(p.x / st), 0), W - 1);
        int row = min(max((int)(p.y / st), 0), H - 1);
        int lseg = b * HW + row * W + col;
        int slot = atomicAdd(&cur[lseg >> TPS_SHIFT], 1);
        float4 r = reg4[i];
        float  o = P.obj[i];
        float2 c = cls2[i];
        pay[2 * (size_t)slot]     = r;
        pay[2 * (size_t)slot + 1] = make_float4(o, c.x, c.y, __int_as_float(lseg));
    }
}

// ---------------------------------------------------------------------------
// Pass 3: one block per tile (788 blocks, 8 KB LDS, 512 thr) — LDS
// accumulate, then fused mean + sigmoid + YOLOX decode, direct output.
// ---------------------------------------------------------------------------
__global__ __launch_bounds__(512) void p3_reduce(const float4* __restrict__ pay,
                                                 const int* __restrict__ tile_base,
                                                 const int* __restrict__ tile_tot,
                                                 float* __restrict__ out)
{
    __shared__ float acc[8][TPS];
    int gt = blockIdx.x, lt;
    int s = tile_scale(gt, lt);
    int HW,W,H,nt,toff,aoff,nblk,srb,nseg; float st;
    scale_consts(s,HW,W,H,st,nt,toff,aoff,nblk,srb,nseg);

    for (int k = threadIdx.x; k < 8 * TPS; k += 512)
        (&acc[0][0])[k] = 0.f;
    __syncthreads();

    int base = tile_base[gt];
    int cnt  = tile_tot[gt];
    int end  = base + cnt;
    int seg0 = lt << TPS_SHIFT;

    int i = base + (int)threadIdx.x;
    for (; i + 512 < end; i += 1024) {
        float4 ra0 = pay[2 * (size_t)i];
        float4 rb0 = pay[2 * (size_t)i + 1];
        float4 ra1 = pay[2 * (size_t)(i + 512)];
        float4 rb1 = pay[2 * (size_t)(i + 512) + 1];
        int l0 = __float_as_int(rb0.w) - seg0;
        int l1 = __float_as_int(rb1.w) - seg0;
        atomicAdd(&acc[0][l0], ra0.x);
        atomicAdd(&acc[1][l0], ra0.y);
        atomicAdd(&acc[2][l0], ra0.z);
        atomicAdd(&acc[3][l0], ra0.w);
        atomicAdd(&acc[4][l0], rb0.x);
        atomicAdd(&acc[5][l0], rb0.y);
        atomicAdd(&acc[6][l0], rb0.z);
        atomicAdd(&acc[7][l0], 1.f);
        atomicAdd(&acc[0][l1], ra1.x);
        atomicAdd(&acc[1][l1], ra1.y);
        atomicAdd(&acc[2][l1], ra1.z);
        atomicAdd(&acc[3][l1], ra1.w);
        atomicAdd(&acc[4][l1], rb1.x);
        atomicAdd(&acc[5][l1], rb1.y);
        atomicAdd(&acc[6][l1], rb1.z);
        atomicAdd(&acc[7][l1], 1.f);
    }
    if (i < end) {
        float4 ra0 = pay[2 * (size_t)i];
        float4 rb0 = pay[2 * (size_t)i + 1];
        int l0 = __float_as_int(rb0.w) - seg0;
        atomicAdd(&acc[0][l0], ra0.x);
        atomicAdd(&acc[1][l0], ra0.y);
        atomicAdd(&acc[2][l0], ra0.z);
        atomicAdd(&acc[3][l0], ra0.w);
        atomicAdd(&acc[4][l0], rb0.x);
        atomicAdd(&acc[5][l0], rb0.y);
        atomicAdd(&acc[6][l0], rb0.z);
        atomicAdd(&acc[7][l0], 1.f);
    }
    __syncthreads();

    int j = threadIdx.x;
    if (j < TPS) {
        int lseg = seg0 + j;                // scale-local segment
        if (lseg < nseg) {
            int b  = lseg / HW;
            int hw = lseg - b * HW;
            int row = hw / W, col = hw - row * W;
            float inv = 1.f / fmaxf(acc[7][j], 1.f);
            float m0 = acc[0][j] * inv, m1 = acc[1][j] * inv;
            float m2 = acc[2][j] * inv, m3 = acc[3][j] * inv;
            float m4 = acc[4][j] * inv, m5 = acc[5][j] * inv, m6 = acc[6][j] * inv;
            float* ob = out + ((size_t)b * A_TOTAL + aoff + hw) * 7;
            ob[0] = (m0 + (float)col) * st;
            ob[1] = (m1 + (float)row) * st;
            ob[2] = expf(fminf(m2, 10.f)) * st;
            ob[3] = expf(fminf(m3, 10.f)) * st;
            ob[4] = 1.f / (1.f + expf(-m4));
            ob[5] = 1.f / (1.f + expf(-m5));
            ob[6] = 1.f / (1.f + expf(-m6));
        }
    }
}

// ---------------------------------------------------------------------------
// Fallback path (round-1, known-correct): global-atomic scatter + finalize.
// ---------------------------------------------------------------------------
__global__ void fb_scatter(const float* __restrict__ cls,
                           const float* __restrict__ reg,
                           const float* __restrict__ obj,
                           const float* __restrict__ pos,
                           const int*   __restrict__ batch,
                           int n, int W, int H, float stride,
                           float* __restrict__ sums, float* __restrict__ counts)
{
    int i   = blockIdx.x * blockDim.x + threadIdx.x;
    int gsz = gridDim.x * blockDim.x;
    for (; i < n; i += gsz) {
        float2 p = reinterpret_cast<const float2*>(pos)[i];
        int b = batch[i];
        int col = min(max((int)(p.x / stride), 0), W - 1);
        int row = min(max((int)(p.y / stride), 0), H - 1);
        int seg = b * (H * W) + row * W + col;
        float4 r = reinterpret_cast<const float4*>(reg)[i];
        float  o = obj[i];
        float2 c = reinterpret_cast<const float2*>(cls)[i];
        float* sb = sums + (size_t)seg * 7;
        atomicAdd(sb + 0, r.x); atomicAdd(sb + 1, r.y);
        atomicAdd(sb + 2, r.z); atomicAdd(sb + 3, r.w);
        atomicAdd(sb + 4, o);   atomicAdd(sb + 5, c.x);
        atomicAdd(sb + 6, c.y); atomicAdd(counts + seg, 1.0f);
    }
}

__global__ void fb_finalize(const float* __restrict__ sums,
                            const float* __restrict__ counts,
                            float* __restrict__ out)
{
    int t = blockIdx.x * blockDim.x + threadIdx.x;
    if (t >= SEG_TOTAL) return;
    int b = t / A_TOTAL;
    int a = t - b * A_TOTAL;
    int hw, Wl, segbase; float stride;
    if (a < 4800)      { hw = a;        Wl = 80; stride = 3.f;  segbase = b * 4800; }
    else if (a < 6000) { hw = a - 4800; Wl = 40; stride = 6.f;  segbase = 153600 + b * 1200; }
    else               { hw = a - 6000; Wl = 20; stride = 12.f; segbase = 192000 + b * 300; }
    int seg = segbase + hw;
    int row = hw / Wl, col = hw - row * Wl;
    const float* sb = sums + (size_t)seg * 7;
    float inv = 1.0f / fmaxf(counts[seg], 1.0f);
    float m0 = sb[0]*inv, m1 = sb[1]*inv, m2 = sb[2]*inv, m3 = sb[3]*inv;
    float m4 = sb[4]*inv, m5 = sb[5]*inv, m6 = sb[6]*inv;
    float* ob = out + (size_t)t * 7;
    ob[0] = (m0 + (float)col) * stride;
    ob[1] = (m1 + (float)row) * stride;
    ob[2] = expf(fminf(m2, 10.f)) * stride;
    ob[3] = expf(fminf(m3, 10.f)) * stride;
    ob[4] = 1.f / (1.f + expf(-m4));
    ob[5] = 1.f / (1.f + expf(-m5));
    ob[6] = 1.f / (1.f + expf(-m6));
}

// ---------------------------------------------------------------------------
extern "C" void kernel_launch(void* const* d_in, const int* in_sizes, int n_in,
                              void* d_out, int out_size, void* d_ws, size_t ws_size,
                              hipStream_t stream)
{
    Args a;
    long long ntot = 0;
    for (int s = 0; s < 3; ++s) {
        a.s[s].cls   = (const float*)d_in[5*s + 0];
        a.s[s].reg   = (const float*)d_in[5*s + 1];
        a.s[s].obj   = (const float*)d_in[5*s + 2];
        a.s[s].pos   = (const float*)d_in[5*s + 3];
        a.s[s].batch = (const int*)  d_in[5*s + 4];
        a.s[s].n = in_sizes[5*s + 2];   // obj has 1 element per point
        ntot += a.s[s].n;
    }
    a.s[0].chunk = (a.s[0].n + NBLK0 - 1) / NBLK0;
    a.s[1].chunk = (a.s[1].n + NBLK1 - 1) / NBLK1;
    a.s[2].chunk = (a.s[2].n + NBLK2 - 1) / NBLK2;

    float* out = (float*)d_out;
    size_t pay_off = 4u << 20;                       // 4 MB
    size_t need = pay_off + (size_t)ntot * 32;

    if (ws_size >= need) {
        int* counts_mat = (int*)d_ws;                         // [MAT_TOT]
        int* rel_base   = counts_mat + MAT_TOT;               // [MAT_TOT]
        int* tile_tot   = rel_base + MAT_TOT;                 // [1024]
        int* tile_base  = tile_tot + 1024;                    // [1024]
        float4* pay = (float4*)((char*)d_ws + pay_off);

        p1_count  <<<NBLK_TOT, 256,  0, stream>>>(a, counts_mat);
        p_scanA   <<<NT_TOT,   512,  0, stream>>>(counts_mat, rel_base, tile_tot);
        p_scanB   <<<1,        1024, 0, stream>>>(tile_tot, tile_base);
        p2_scatter<<<NBLK_TOT, 256,  0, stream>>>(a, rel_base, tile_base, pay);
        p3_reduce <<<NT_TOT,   512,  0, stream>>>(pay, tile_base, tile_tot, out);
    } else {
        // Fallback: known-correct atomic path
        float* sums   = (float*)d_ws;                       // [SEG_TOTAL][7]
        float* counts = sums + (size_t)SEG_TOTAL * 7;       // [SEG_TOTAL]
        hipMemsetAsync(d_ws, 0, (size_t)SEG_TOTAL * 8 * sizeof(float), stream);
        const int   Ws[3] = {80, 40, 20};
        const int   Hs[3] = {60, 30, 15};
        const float Ss[3] = {3.f, 6.f, 12.f};
        const int   So[3] = {0, 153600, 192000};
        for (int s = 0; s < 3; ++s) {
            int n = a.s[s].n;
            int blocks = min((n + 255) / 256, 2048);
            fb_scatter<<<blocks, 256, 0, stream>>>(
                a.s[s].cls, a.s[s].reg, a.s[s].obj, a.s[s].pos, a.s[s].batch,
                n, Ws[s], Hs[s], Ss[s],
                sums + (size_t)So[s] * 7, counts + So[s]);
        }
        fb_finalize<<<(SEG_TOTAL + 255) / 256, 256, 0, stream>>>(sums, counts, out);
    }
}

// Round 4
// 507.938 us; speedup vs baseline: 1.4256x; 1.4256x over previous
//
#include <hip/hip_runtime.h>
#include <hip/hip_bf16.h>

// ---------------------------------------------------------------------------
// Problem constants
// ---------------------------------------------------------------------------
#define NUM_B     32
#define A_TOTAL   6300
#define SEG_TOTAL 201600
#define MAXNT     600          // max tiles per scale (scale 0)
#define NT_TOT    1200         // 600 + 300 + 300
#define NBLK0     512
#define NBLK1     256
#define NBLK2     128
#define NBLK_TOT  896
#define MAT_TOT   422400       // 600*512 + 300*256 + 300*128

struct Ptrs {
    const float* cls; const float* reg; const float* obj;
    const float* pos; const int* batch;
    int n, chunk;
};
struct Args { Ptrs s[3]; };

struct SC { int HW, W, H, nt, toff, aoff, nblk, srb, shift, tps, nseg; float st; };

__device__ __forceinline__ SC get_sc(int s)
{
    if (s == 0) return {4800, 80, 60, 600, 0,   0,    NBLK0, 0,      8, 256, 153600, 3.f};
    if (s == 1) return {1200, 40, 30, 300, 600, 4800, NBLK1, 307200, 7, 128, 38400,  6.f};
    return            {300,  20, 15, 300, 900, 6000, NBLK2, 384000, 5, 32,  9600,   12.f};
}

__device__ __forceinline__ int block_scale(int bid, int& lb)
{
    if (bid < NBLK0)         { lb = bid;                   return 0; }
    if (bid < NBLK0 + NBLK1) { lb = bid - NBLK0;           return 1; }
    lb = bid - (NBLK0 + NBLK1);                            return 2;
}

__device__ __forceinline__ int tile_scale(int gt, int& lt)
{
    if (gt < 600) { lt = gt;       return 0; }
    if (gt < 900) { lt = gt - 600; return 1; }
    lt = gt - 900;                 return 2;
}

// Native LDS fp32 atomic add, fire-and-forget (no rtn -> no lgkmcnt stall).
// Flat shared pointers have the LDS byte offset in their low 32 bits
// (4 GB-aligned shared aperture).
__device__ __forceinline__ void lds_fadd(float* p, float v)
{
    unsigned int off = (unsigned int)(uintptr_t)p;
    asm volatile("ds_add_f32 %0, %1" :: "v"(off), "v"(v) : "memory");
}

// f32 -> bf16 (round-to-nearest-even), as low 16 bits of a u32
__device__ __forceinline__ unsigned int f2bf(float f)
{
    unsigned int u = __float_as_uint(f);
    return (u + 0x7fffu + ((u >> 16) & 1u)) >> 16;
}

// ---------------------------------------------------------------------------
// Pass 1: per-(block,tile) histogram -> counts_mat (fully rewritten per call)
// ---------------------------------------------------------------------------
__global__ __launch_bounds__(256) void p1_count(Args a, int* __restrict__ counts_mat)
{
    __shared__ int hist[MAXNT];
    int lb; int s = block_scale(blockIdx.x, lb);
    SC c = get_sc(s);
    const Ptrs& P = a.s[s];

    for (int t = threadIdx.x; t < c.nt; t += 256) hist[t] = 0;
    __syncthreads();

    int start = lb * P.chunk;
    int end   = min(start + P.chunk, P.n);
    const float2* pos = reinterpret_cast<const float2*>(P.pos);
    for (int i = start + (int)threadIdx.x; i < end; i += 256) {
        float2 p = pos[i];
        int b = P.batch[i];
        int col = min(max((int)(p.x / c.st), 0), c.W - 1);
        int row = min(max((int)(p.y / c.st), 0), c.H - 1);
        int lseg = b * c.HW + row * c.W + col;
        atomicAdd(&hist[lseg >> c.shift], 1);
    }
    __syncthreads();
    for (int t = threadIdx.x; t < c.nt; t += 256)
        counts_mat[c.srb + t * c.nblk + lb] = hist[t];
}

// ---------------------------------------------------------------------------
// Scan A: one block per tile — exclusive scan over per-block counts.
// ---------------------------------------------------------------------------
__global__ __launch_bounds__(512) void p_scanA(const int* __restrict__ counts_mat,
                                               int* __restrict__ rel_base,
                                               int* __restrict__ tile_tot)
{
    __shared__ int buf[512];
    int gt = blockIdx.x, lt;
    int s = tile_scale(gt, lt);
    SC c = get_sc(s);
    int row = c.srb + lt * c.nblk;
    int t = threadIdx.x;
    int v = (t < c.nblk) ? counts_mat[row + t] : 0;
    buf[t] = v;
    __syncthreads();
    int x = v;
    for (int off = 1; off < 512; off <<= 1) {
        int y = (t >= off) ? buf[t - off] : 0;
        __syncthreads();
        x += y;
        buf[t] = x;
        __syncthreads();
    }
    if (t < c.nblk) rel_base[row + t] = x - v;
    if (t == c.nblk - 1) tile_tot[gt] = x;
}

// ---------------------------------------------------------------------------
// Scan B: exclusive scan over 1200 tile totals (single block, ping-pong)
// ---------------------------------------------------------------------------
__global__ __launch_bounds__(1024) void p_scanB(const int* __restrict__ tile_tot,
                                                int* __restrict__ tile_base)
{
    __shared__ int bufA[NT_TOT], bufB[NT_TOT];
    int t = threadIdx.x;
    for (int k = t; k < NT_TOT; k += 1024) bufA[k] = tile_tot[k];
    __syncthreads();
    int* src = bufA; int* dst = bufB;
    for (int off = 1; off < NT_TOT; off <<= 1) {
        for (int k = t; k < NT_TOT; k += 1024)
            dst[k] = src[k] + ((k >= off) ? src[k - off] : 0);
        __syncthreads();
        int* tmp = src; src = dst; dst = tmp;
    }
    for (int k = t; k < NT_TOT; k += 1024) tile_base[k] = src[k] - tile_tot[k];
}

// ---------------------------------------------------------------------------
// Pass 2: single sweep — LDS cursors seeded from tile_base+rel_base, write
// 16 B bf16-packed payload per point into tile-sorted order.
// payload u32s: {bf(rx)|bf(ry)<<16, bf(rz)|bf(rw)<<16, bf(o)|bf(cx)<<16,
//               bf(cy)|local_seg<<16}
// ---------------------------------------------------------------------------
__global__ __launch_bounds__(256) void p2_scatter(Args a,
                                                  const int* __restrict__ rel_base,
                                                  const int* __restrict__ tile_base,
                                                  uint4* __restrict__ pay)
{
    __shared__ int cur[MAXNT];
    int lb; int s = block_scale(blockIdx.x, lb);
    SC c = get_sc(s);
    const Ptrs& P = a.s[s];

    for (int t = threadIdx.x; t < c.nt; t += 256)
        cur[t] = tile_base[c.toff + t] + rel_base[c.srb + t * c.nblk + lb];
    __syncthreads();

    int start = lb * P.chunk;
    int end   = min(start + P.chunk, P.n);
    const float2* pos  = reinterpret_cast<const float2*>(P.pos);
    const float4* reg4 = reinterpret_cast<const float4*>(P.reg);
    const float2* cls2 = reinterpret_cast<const float2*>(P.cls);
    unsigned int lmask = (unsigned int)(c.tps - 1);

    for (int i = start + (int)threadIdx.x; i < end; i += 256) {
        float2 p = pos[i];
        int b = P.batch[i];
        int col = min(max((int)(p.x / c.st), 0), c.W - 1);
        int row = min(max((int)(p.y / c.st), 0), c.H - 1);
        int lseg = b * c.HW + row * c.W + col;
        int slot = atomicAdd(&cur[lseg >> c.shift], 1);
        float4 r = reg4[i];
        float  o = P.obj[i];
        float2 cl = cls2[i];
        uint4 w;
        w.x = f2bf(r.x) | (f2bf(r.y) << 16);
        w.y = f2bf(r.z) | (f2bf(r.w) << 16);
        w.z = f2bf(o)   | (f2bf(cl.x) << 16);
        w.w = f2bf(cl.y) | (((unsigned int)lseg & lmask) << 16);
        pay[slot] = w;
    }
}

// ---------------------------------------------------------------------------
// Pass 3: one block per tile (1200 blocks, 256 thr, 8 KB LDS) — native
// ds_add_f32 accumulate, then fused mean + sigmoid + YOLOX decode.
// ---------------------------------------------------------------------------
__device__ __forceinline__ void p3_point(const uint4* __restrict__ pay, int i,
                                         float (*acc)[256])
{
    uint4 w = pay[i];
    int l = (int)(w.w >> 16);
    lds_fadd(&acc[0][l], __uint_as_float(w.x << 16));
    lds_fadd(&acc[1][l], __uint_as_float(w.x & 0xffff0000u));
    lds_fadd(&acc[2][l], __uint_as_float(w.y << 16));
    lds_fadd(&acc[3][l], __uint_as_float(w.y & 0xffff0000u));
    lds_fadd(&acc[4][l], __uint_as_float(w.z << 16));
    lds_fadd(&acc[5][l], __uint_as_float(w.z & 0xffff0000u));
    lds_fadd(&acc[6][l], __uint_as_float(w.w << 16));
    lds_fadd(&acc[7][l], 1.0f);
}

__global__ __launch_bounds__(256) void p3_reduce(const uint4* __restrict__ pay,
                                                 const int* __restrict__ tile_base,
                                                 const int* __restrict__ tile_tot,
                                                 float* __restrict__ out)
{
    __shared__ float acc[8][256];
    int gt = blockIdx.x, lt;
    int s = tile_scale(gt, lt);
    SC c = get_sc(s);

    for (int k = threadIdx.x; k < 8 * 256; k += 256)
        (&acc[0][0])[k] = 0.f;
    __syncthreads();

    int base = tile_base[gt];
    int lim  = base + tile_tot[gt];

    int i = base + (int)threadIdx.x;
    for (; i + 256 < lim; i += 512) {
        p3_point(pay, i,       acc);
        p3_point(pay, i + 256, acc);
    }
    if (i < lim) p3_point(pay, i, acc);
    __syncthreads();

    int j = threadIdx.x;
    if (j < c.tps) {
        int lseg = (lt << c.shift) + j;          // scale-local segment
        int b  = lseg / c.HW;
        int hw = lseg - b * c.HW;
        int row = hw / c.W, col = hw - row * c.W;
        float inv = 1.f / fmaxf(acc[7][j], 1.f);
        float m0 = acc[0][j] * inv, m1 = acc[1][j] * inv;
        float m2 = acc[2][j] * inv, m3 = acc[3][j] * inv;
        float m4 = acc[4][j] * inv, m5 = acc[5][j] * inv, m6 = acc[6][j] * inv;
        float* ob = out + ((size_t)b * A_TOTAL + c.aoff + hw) * 7;
        ob[0] = (m0 + (float)col) * c.st;
        ob[1] = (m1 + (float)row) * c.st;
        ob[2] = expf(fminf(m2, 10.f)) * c.st;
        ob[3] = expf(fminf(m3, 10.f)) * c.st;
        ob[4] = 1.f / (1.f + expf(-m4));
        ob[5] = 1.f / (1.f + expf(-m5));
        ob[6] = 1.f / (1.f + expf(-m6));
    }
}

// ---------------------------------------------------------------------------
// Fallback path (round-1, known-correct): global-atomic scatter + finalize.
// ---------------------------------------------------------------------------
__global__ void fb_scatter(const float* __restrict__ cls,
                           const float* __restrict__ reg,
                           const float* __restrict__ obj,
                           const float* __restrict__ pos,
                           const int*   __restrict__ batch,
                           int n, int W, int H, float stride,
                           float* __restrict__ sums, float* __restrict__ counts)
{
    int i   = blockIdx.x * blockDim.x + threadIdx.x;
    int gsz = gridDim.x * blockDim.x;
    for (; i < n; i += gsz) {
        float2 p = reinterpret_cast<const float2*>(pos)[i];
        int b = batch[i];
        int col = min(max((int)(p.x / stride), 0), W - 1);
        int row = min(max((int)(p.y / stride), 0), H - 1);
        int seg = b * (H * W) + row * W + col;
        float4 r = reinterpret_cast<const float4*>(reg)[i];
        float  o = obj[i];
        float2 c = reinterpret_cast<const float2*>(cls)[i];
        float* sb = sums + (size_t)seg * 7;
        atomicAdd(sb + 0, r.x); atomicAdd(sb + 1, r.y);
        atomicAdd(sb + 2, r.z); atomicAdd(sb + 3, r.w);
        atomicAdd(sb + 4, o);   atomicAdd(sb + 5, c.x);
        atomicAdd(sb + 6, c.y); atomicAdd(counts + seg, 1.0f);
    }
}

__global__ void fb_finalize(const float* __restrict__ sums,
                            const float* __restrict__ counts,
                            float* __restrict__ out)
{
    int t = blockIdx.x * blockDim.x + threadIdx.x;
    if (t >= SEG_TOTAL) return;
    int b = t / A_TOTAL;
    int a = t - b * A_TOTAL;
    int hw, Wl, segbase; float stride;
    if (a < 4800)      { hw = a;        Wl = 80; stride = 3.f;  segbase = b * 4800; }
    else if (a < 6000) { hw = a - 4800; Wl = 40; stride = 6.f;  segbase = 153600 + b * 1200; }
    else               { hw = a - 6000; Wl = 20; stride = 12.f; segbase = 192000 + b * 300; }
    int seg = segbase + hw;
    int row = hw / Wl, col = hw - row * Wl;
    const float* sb = sums + (size_t)seg * 7;
    float inv = 1.0f / fmaxf(counts[seg], 1.0f);
    float m0 = sb[0]*inv, m1 = sb[1]*inv, m2 = sb[2]*inv, m3 = sb[3]*inv;
    float m4 = sb[4]*inv, m5 = sb[5]*inv, m6 = sb[6]*inv;
    float* ob = out + (size_t)t * 7;
    ob[0] = (m0 + (float)col) * stride;
    ob[1] = (m1 + (float)row) * stride;
    ob[2] = expf(fminf(m2, 10.f)) * stride;
    ob[3] = expf(fminf(m3, 10.f)) * stride;
    ob[4] = 1.f / (1.f + expf(-m4));
    ob[5] = 1.f / (1.f + expf(-m5));
    ob[6] = 1.f / (1.f + expf(-m6));
}

// ---------------------------------------------------------------------------
extern "C" void kernel_launch(void* const* d_in, const int* in_sizes, int n_in,
                              void* d_out, int out_size, void* d_ws, size_t ws_size,
                              hipStream_t stream)
{
    Args a;
    long long ntot = 0;
    for (int s = 0; s < 3; ++s) {
        a.s[s].cls   = (const float*)d_in[5*s + 0];
        a.s[s].reg   = (const float*)d_in[5*s + 1];
        a.s[s].obj   = (const float*)d_in[5*s + 2];
        a.s[s].pos   = (const float*)d_in[5*s + 3];
        a.s[s].batch = (const int*)  d_in[5*s + 4];
        a.s[s].n = in_sizes[5*s + 2];   // obj has 1 element per point
        ntot += a.s[s].n;
    }
    a.s[0].chunk = (a.s[0].n + NBLK0 - 1) / NBLK0;
    a.s[1].chunk = (a.s[1].n + NBLK1 - 1) / NBLK1;
    a.s[2].chunk = (a.s[2].n + NBLK2 - 1) / NBLK2;

    float* out = (float*)d_out;
    size_t pay_off = 4u << 20;                       // 4 MB for metadata
    size_t need = pay_off + (size_t)ntot * 16;

    if (ws_size >= need) {
        int* counts_mat = (int*)d_ws;                         // [MAT_TOT]
        int* rel_base   = counts_mat + MAT_TOT;               // [MAT_TOT]
        int* tile_tot   = rel_base + MAT_TOT;                 // [2048]
        int* tile_base  = tile_tot + 2048;                    // [2048]
        uint4* pay = (uint4*)((char*)d_ws + pay_off);

        p1_count  <<<NBLK_TOT, 256,  0, stream>>>(a, counts_mat);
        p_scanA   <<<NT_TOT,   512,  0, stream>>>(counts_mat, rel_base, tile_tot);
        p_scanB   <<<1,        1024, 0, stream>>>(tile_tot, tile_base);
        p2_scatter<<<NBLK_TOT, 256,  0, stream>>>(a, rel_base, tile_base, pay);
        p3_reduce <<<NT_TOT,   256,  0, stream>>>(pay, tile_base, tile_tot, out);
    } else {
        // Fallback: known-correct atomic path
        float* sums   = (float*)d_ws;                       // [SEG_TOTAL][7]
        float* counts = sums + (size_t)SEG_TOTAL * 7;       // [SEG_TOTAL]
        hipMemsetAsync(d_ws, 0, (size_t)SEG_TOTAL * 8 * sizeof(float), stream);
        const int   Ws[3] = {80, 40, 20};
        const int   Hs[3] = {60, 30, 15};
        const float Ss[3] = {3.f, 6.f, 12.f};
        const int   So[3] = {0, 153600, 192000};
        for (int s = 0; s < 3; ++s) {
            int n = a.s[s].n;
            int blocks = min((n + 255) / 256, 2048);
            fb_scatter<<<blocks, 256, 0, stream>>>(
                a.s[s].cls, a.s[s].reg, a.s[s].obj, a.s[s].pos, a.s[s].batch,
                n, Ws[s], Hs[s], Ss[s],
                sums + (size_t)So[s] * 7, counts + So[s]);
        }
        fb_finalize<<<(SEG_TOTAL + 255) / 256, 256, 0, stream>>>(sums, counts, out);
    }
}

// Round 5
// 363.818 us; speedup vs baseline: 1.9903x; 1.3961x over previous
//
#include <hip/hip_runtime.h>
#include <hip/hip_bf16.h>

// ---------------------------------------------------------------------------
// Problem constants.  Tile order: scale2 (75 tiles, heavy) first, then
// scale1 (300), then scale0 (600).  tps = 256/128/128 cells.
// ---------------------------------------------------------------------------
#define NUM_B     32
#define A_TOTAL   6300
#define SEG_TOTAL 201600
#define MAXNT     600
#define NT_TOT    975          // 75 + 300 + 600
#define NBLK0     512
#define NBLK1     256
#define NBLK2     128
#define NBLK_TOT  896
#define MAT_TOT   393600       // 75*128 + 300*256 + 600*512

struct Ptrs {
    const float* cls; const float* reg; const float* obj;
    const float* pos; const int* batch;
    int n, chunk;
};
struct Args { Ptrs s[3]; };

struct SC { int HW, W, H, nt, toff, aoff, nblk, srb, shift, tps, nseg; float st; };

__device__ __forceinline__ SC get_sc(int s)
{
    if (s == 0) return {4800, 80, 60, 600, 375, 0,    NBLK0, 86400, 8, 256, 153600, 3.f};
    if (s == 1) return {1200, 40, 30, 300, 75,  4800, NBLK1, 9600,  7, 128, 38400,  6.f};
    return            {300,  20, 15, 75,  0,   6000, NBLK2, 0,     7, 128, 9600,   12.f};
}

__device__ __forceinline__ int block_scale(int bid, int& lb)
{
    if (bid < NBLK0)         { lb = bid;                   return 0; }
    if (bid < NBLK0 + NBLK1) { lb = bid - NBLK0;           return 1; }
    lb = bid - (NBLK0 + NBLK1);                            return 2;
}

// tile order: [0,75) scale2, [75,375) scale1, [375,975) scale0
__device__ __forceinline__ int tile_scale(int gt, int& lt)
{
    if (gt < 75)  { lt = gt;       return 2; }
    if (gt < 375) { lt = gt - 75;  return 1; }
    lt = gt - 375;                 return 0;
}

// f32 -> bf16 (round-to-nearest-even), low 16 bits of a u32
__device__ __forceinline__ unsigned int f2bf(float f)
{
    unsigned int u = __float_as_uint(f);
    return (u + 0x7fffu + ((u >> 16) & 1u)) >> 16;
}

__device__ __forceinline__ float bf_lo(unsigned int u) { return __uint_as_float(u << 16); }
__device__ __forceinline__ float bf_hi(unsigned int u) { return __uint_as_float(u & 0xffff0000u); }

// ---------------------------------------------------------------------------
// Pass 1: per-(block,tile) histogram -> counts_mat (fully rewritten per call)
// ---------------------------------------------------------------------------
__global__ __launch_bounds__(256) void p1_count(Args a, int* __restrict__ counts_mat)
{
    __shared__ int hist[MAXNT];
    int lb; int s = block_scale(blockIdx.x, lb);
    SC c = get_sc(s);
    const Ptrs& P = a.s[s];

    for (int t = threadIdx.x; t < c.nt; t += 256) hist[t] = 0;
    __syncthreads();

    int start = lb * P.chunk;
    int end   = min(start + P.chunk, P.n);
    const float2* pos = reinterpret_cast<const float2*>(P.pos);
    for (int i = start + (int)threadIdx.x; i < end; i += 256) {
        float2 p = pos[i];
        int b = P.batch[i];
        int col = min(max((int)(p.x / c.st), 0), c.W - 1);
        int row = min(max((int)(p.y / c.st), 0), c.H - 1);
        int lseg = b * c.HW + row * c.W + col;
        atomicAdd(&hist[lseg >> c.shift], 1);
    }
    __syncthreads();
    for (int t = threadIdx.x; t < c.nt; t += 256)
        counts_mat[c.srb + t * c.nblk + lb] = hist[t];
}

// ---------------------------------------------------------------------------
// Scan A: one block per tile — exclusive scan over per-block counts.
// ---------------------------------------------------------------------------
__global__ __launch_bounds__(512) void p_scanA(const int* __restrict__ counts_mat,
                                               int* __restrict__ rel_base,
                                               int* __restrict__ tile_tot)
{
    __shared__ int buf[512];
    int gt = blockIdx.x, lt;
    int s = tile_scale(gt, lt);
    SC c = get_sc(s);
    int row = c.srb + lt * c.nblk;
    int t = threadIdx.x;
    int v = (t < c.nblk) ? counts_mat[row + t] : 0;
    buf[t] = v;
    __syncthreads();
    int x = v;
    for (int off = 1; off < 512; off <<= 1) {
        int y = (t >= off) ? buf[t - off] : 0;
        __syncthreads();
        x += y;
        buf[t] = x;
        __syncthreads();
    }
    if (t < c.nblk) rel_base[row + t] = x - v;
    if (t == c.nblk - 1) tile_tot[gt] = x;
}

// ---------------------------------------------------------------------------
// Scan B: exclusive scan over 975 tile totals (single block)
// ---------------------------------------------------------------------------
__global__ __launch_bounds__(1024) void p_scanB(const int* __restrict__ tile_tot,
                                                int* __restrict__ tile_base)
{
    __shared__ int buf[1024];
    int t = threadIdx.x;
    int v = (t < NT_TOT) ? tile_tot[t] : 0;
    buf[t] = v;
    __syncthreads();
    int x = v;
    for (int off = 1; off < 1024; off <<= 1) {
        int y = (t >= off) ? buf[t - off] : 0;
        __syncthreads();
        x += y;
        buf[t] = x;
        __syncthreads();
    }
    if (t < NT_TOT) tile_base[t] = x - v;
}

// ---------------------------------------------------------------------------
// Pass 2: single sweep — LDS cursors seeded from tile_base+rel_base, write
// 16 B bf16-packed payload per point into tile-sorted order.
// payload u32s: {bf(rx)|bf(ry)<<16, bf(rz)|bf(rw)<<16, bf(o)|bf(cx)<<16,
//               bf(cy)|local_seg<<16}
// ---------------------------------------------------------------------------
__global__ __launch_bounds__(256) void p2_scatter(Args a,
                                                  const int* __restrict__ rel_base,
                                                  const int* __restrict__ tile_base,
                                                  uint4* __restrict__ pay)
{
    __shared__ int cur[MAXNT];
    int lb; int s = block_scale(blockIdx.x, lb);
    SC c = get_sc(s);
    const Ptrs& P = a.s[s];

    for (int t = threadIdx.x; t < c.nt; t += 256)
        cur[t] = tile_base[c.toff + t] + rel_base[c.srb + t * c.nblk + lb];
    __syncthreads();

    int start = lb * P.chunk;
    int end   = min(start + P.chunk, P.n);
    const float2* pos  = reinterpret_cast<const float2*>(P.pos);
    const float4* reg4 = reinterpret_cast<const float4*>(P.reg);
    const float2* cls2 = reinterpret_cast<const float2*>(P.cls);
    unsigned int lmask = (unsigned int)(c.tps - 1);

    for (int i = start + (int)threadIdx.x; i < end; i += 256) {
        float2 p = pos[i];
        int b = P.batch[i];
        int col = min(max((int)(p.x / c.st), 0), c.W - 1);
        int row = min(max((int)(p.y / c.st), 0), c.H - 1);
        int lseg = b * c.HW + row * c.W + col;
        int slot = atomicAdd(&cur[lseg >> c.shift], 1);
        float4 r = reg4[i];
        float  o = P.obj[i];
        float2 cl = cls2[i];
        uint4 w;
        w.x = f2bf(r.x) | (f2bf(r.y) << 16);
        w.y = f2bf(r.z) | (f2bf(r.w) << 16);
        w.z = f2bf(o)   | (f2bf(cl.x) << 16);
        w.w = f2bf(cl.y) | (((unsigned int)lseg & lmask) << 16);
        pay[slot] = w;
    }
}

// ---------------------------------------------------------------------------
// Pass 3: one block per tile (975 blocks, 512 thr, 4 KB LDS).
// Accumulator: acc[word][256], each word = 2 packed bf16 channels.
// 4× ds_pk_add_bf16 per point (no return, no "memory" clobber -> loads
// stay pipelined; __syncthreads orders everything before the read-back).
// ---------------------------------------------------------------------------
__device__ __forceinline__ void point_add(unsigned int abase, uint4 w)
{
    unsigned int off = abase + ((w.w >> 16) << 2);          // cell byte offset
    unsigned int d3  = (w.w & 0xffffu) | 0x3f800000u;       // (cy, 1.0bf16)
    asm volatile("ds_pk_add_bf16 %0, %1"             :: "v"(off), "v"(w.x));
    asm volatile("ds_pk_add_bf16 %0, %1 offset:1024" :: "v"(off), "v"(w.y));
    asm volatile("ds_pk_add_bf16 %0, %1 offset:2048" :: "v"(off), "v"(w.z));
    asm volatile("ds_pk_add_bf16 %0, %1 offset:3072" :: "v"(off), "v"(d3));
}

__global__ __launch_bounds__(512) void p3_reduce(const uint4* __restrict__ pay,
                                                 const int* __restrict__ tile_base,
                                                 const int* __restrict__ tile_tot,
                                                 float* __restrict__ out)
{
    __shared__ unsigned int acc[4][256];
    int gt = blockIdx.x, lt;
    int s = tile_scale(gt, lt);
    SC c = get_sc(s);

    for (int k = threadIdx.x; k < 4 * 256; k += 512)
        (&acc[0][0])[k] = 0u;
    __syncthreads();

    unsigned int abase = (unsigned int)(uintptr_t)&acc[0][0];
    int base = tile_base[gt];
    int lim  = base + tile_tot[gt];

    int i = base + (int)threadIdx.x;
    // 4-deep batched loads, then the atomic cluster
    for (; i + 1536 < lim; i += 2048) {
        uint4 w0 = pay[i];
        uint4 w1 = pay[i + 512];
        uint4 w2 = pay[i + 1024];
        uint4 w3 = pay[i + 1536];
        point_add(abase, w0);
        point_add(abase, w1);
        point_add(abase, w2);
        point_add(abase, w3);
    }
    for (; i < lim; i += 512)
        point_add(abase, pay[i]);
    __syncthreads();

    int j = threadIdx.x;
    if (j < c.tps) {
        unsigned int a0 = acc[0][j], a1 = acc[1][j];
        unsigned int a2 = acc[2][j], a3 = acc[3][j];
        float cnt = bf_hi(a3);                   // exact integer <= 256
        float inv = 1.f / fmaxf(cnt, 1.f);
        float m0 = bf_lo(a0) * inv, m1 = bf_hi(a0) * inv;
        float m2 = bf_lo(a1) * inv, m3 = bf_hi(a1) * inv;
        float m4 = bf_lo(a2) * inv, m5 = bf_hi(a2) * inv;
        float m6 = bf_lo(a3) * inv;
        int lseg = (lt << c.shift) + j;          // scale-local segment
        int b  = lseg / c.HW;
        int hw = lseg - b * c.HW;
        int row = hw / c.W, col = hw - row * c.W;
        float* ob = out + ((size_t)b * A_TOTAL + c.aoff + hw) * 7;
        ob[0] = (m0 + (float)col) * c.st;
        ob[1] = (m1 + (float)row) * c.st;
        ob[2] = expf(fminf(m2, 10.f)) * c.st;
        ob[3] = expf(fminf(m3, 10.f)) * c.st;
        ob[4] = 1.f / (1.f + expf(-m4));
        ob[5] = 1.f / (1.f + expf(-m5));
        ob[6] = 1.f / (1.f + expf(-m6));
    }
}

// ---------------------------------------------------------------------------
// Fallback path (round-1, known-correct): global-atomic scatter + finalize.
// ---------------------------------------------------------------------------
__global__ void fb_scatter(const float* __restrict__ cls,
                           const float* __restrict__ reg,
                           const float* __restrict__ obj,
                           const float* __restrict__ pos,
                           const int*   __restrict__ batch,
                           int n, int W, int H, float stride,
                           float* __restrict__ sums, float* __restrict__ counts)
{
    int i   = blockIdx.x * blockDim.x + threadIdx.x;
    int gsz = gridDim.x * blockDim.x;
    for (; i < n; i += gsz) {
        float2 p = reinterpret_cast<const float2*>(pos)[i];
        int b = batch[i];
        int col = min(max((int)(p.x / stride), 0), W - 1);
        int row = min(max((int)(p.y / stride), 0), H - 1);
        int seg = b * (H * W) + row * W + col;
        float4 r = reinterpret_cast<const float4*>(reg)[i];
        float  o = obj[i];
        float2 c = reinterpret_cast<const float2*>(cls)[i];
        float* sb = sums + (size_t)seg * 7;
        atomicAdd(sb + 0, r.x); atomicAdd(sb + 1, r.y);
        atomicAdd(sb + 2, r.z); atomicAdd(sb + 3, r.w);
        atomicAdd(sb + 4, o);   atomicAdd(sb + 5, c.x);
        atomicAdd(sb + 6, c.y); atomicAdd(counts + seg, 1.0f);
    }
}

__global__ void fb_finalize(const float* __restrict__ sums,
                            const float* __restrict__ counts,
                            float* __restrict__ out)
{
    int t = blockIdx.x * blockDim.x + threadIdx.x;
    if (t >= SEG_TOTAL) return;
    int b = t / A_TOTAL;
    int a = t - b * A_TOTAL;
    int hw, Wl, segbase; float stride;
    if (a < 4800)      { hw = a;        Wl = 80; stride = 3.f;  segbase = b * 4800; }
    else if (a < 6000) { hw = a - 4800; Wl = 40; stride = 6.f;  segbase = 153600 + b * 1200; }
    else               { hw = a - 6000; Wl = 20; stride = 12.f; segbase = 192000 + b * 300; }
    int seg = segbase + hw;
    int row = hw / Wl, col = hw - row * Wl;
    const float* sb = sums + (size_t)seg * 7;
    float inv = 1.0f / fmaxf(counts[seg], 1.0f);
    float m0 = sb[0]*inv, m1 = sb[1]*inv, m2 = sb[2]*inv, m3 = sb[3]*inv;
    float m4 = sb[4]*inv, m5 = sb[5]*inv, m6 = sb[6]*inv;
    float* ob = out + (size_t)t * 7;
    ob[0] = (m0 + (float)col) * stride;
    ob[1] = (m1 + (float)row) * stride;
    ob[2] = expf(fminf(m2, 10.f)) * stride;
    ob[3] = expf(fminf(m3, 10.f)) * stride;
    ob[4] = 1.f / (1.f + expf(-m4));
    ob[5] = 1.f / (1.f + expf(-m5));
    ob[6] = 1.f / (1.f + expf(-m6));
}

// ---------------------------------------------------------------------------
extern "C" void kernel_launch(void* const* d_in, const int* in_sizes, int n_in,
                              void* d_out, int out_size, void* d_ws, size_t ws_size,
                              hipStream_t stream)
{
    Args a;
    long long ntot = 0;
    for (int s = 0; s < 3; ++s) {
        a.s[s].cls   = (const float*)d_in[5*s + 0];
        a.s[s].reg   = (const float*)d_in[5*s + 1];
        a.s[s].obj   = (const float*)d_in[5*s + 2];
        a.s[s].pos   = (const float*)d_in[5*s + 3];
        a.s[s].batch = (const int*)  d_in[5*s + 4];
        a.s[s].n = in_sizes[5*s + 2];   // obj has 1 element per point
        ntot += a.s[s].n;
    }
    a.s[0].chunk = (a.s[0].n + NBLK0 - 1) / NBLK0;
    a.s[1].chunk = (a.s[1].n + NBLK1 - 1) / NBLK1;
    a.s[2].chunk = (a.s[2].n + NBLK2 - 1) / NBLK2;

    float* out = (float*)d_out;
    size_t pay_off = 4u << 20;                       // 4 MB for metadata
    size_t need = pay_off + (size_t)ntot * 16;

    if (ws_size >= need) {
        int* counts_mat = (int*)d_ws;                         // [MAT_TOT]
        int* rel_base   = counts_mat + MAT_TOT;               // [MAT_TOT]
        int* tile_tot   = rel_base + MAT_TOT;                 // [1024]
        int* tile_base  = tile_tot + 1024;                    // [1024]
        uint4* pay = (uint4*)((char*)d_ws + pay_off);

        p1_count  <<<NBLK_TOT, 256,  0, stream>>>(a, counts_mat);
        p_scanA   <<<NT_TOT,   512,  0, stream>>>(counts_mat, rel_base, tile_tot);
        p_scanB   <<<1,        1024, 0, stream>>>(tile_tot, tile_base);
        p2_scatter<<<NBLK_TOT, 256,  0, stream>>>(a, rel_base, tile_base, pay);
        p3_reduce <<<NT_TOT,   512,  0, stream>>>(pay, tile_base, tile_tot, out);
    } else {
        // Fallback: known-correct atomic path
        float* sums   = (float*)d_ws;                       // [SEG_TOTAL][7]
        float* counts = sums + (size_t)SEG_TOTAL * 7;       // [SEG_TOTAL]
        hipMemsetAsync(d_ws, 0, (size_t)SEG_TOTAL * 8 * sizeof(float), stream);
        const int   Ws[3] = {80, 40, 20};
        const int   Hs[3] = {60, 30, 15};
        const float Ss[3] = {3.f, 6.f, 12.f};
        const int   So[3] = {0, 153600, 192000};
        for (int s = 0; s < 3; ++s) {
            int n = a.s[s].n;
            int blocks = min((n + 255) / 256, 2048);
            fb_scatter<<<blocks, 256, 0, stream>>>(
                a.s[s].cls, a.s[s].reg, a.s[s].obj, a.s[s].pos, a.s[s].batch,
                n, Ws[s], Hs[s], Ss[s],
                sums + (size_t)So[s] * 7, counts + So[s]);
        }
        fb_finalize<<<(SEG_TOTAL + 255) / 256, 256, 0, stream>>>(sums, counts, out);
    }
}